// Round 1
// baseline (220.341 us; speedup 1.0000x reference)
//
#include <hip/hip_runtime.h>

#define KLEN 2048
#define BLK 256
#define NEGV (-1e4f)
#define LCC 2.0f

struct SM {
  float y1[KLEN];
  float y2[KLEN];
  float y3[KLEN];
  float Lint[KLEN];
  float A[KLEN];            // Le1 buffer; also reused as int bit buffer during encode
  unsigned short perm[KLEN];
  float scan[16 * BLK];     // column-major: scan[e*BLK + c]
};

__device__ __forceinline__ float max16(const float* M) {
  float m = M[0];
#pragma unroll
  for (int e = 1; e < 16; ++e) m = fmaxf(m, M[e]);
  return m;
}

// Z = X (x) Y  in max-plus: Z[i][j] = max_k X[i][k] + Y[k][j]
__device__ __forceinline__ void combine16(const float* X, const float* Y, float* Z) {
#pragma unroll
  for (int i = 0; i < 4; ++i) {
#pragma unroll
    for (int j = 0; j < 4; ++j) {
      float r = X[i*4+0] + Y[0*4+j];
      r = fmaxf(r, X[i*4+1] + Y[1*4+j]);
      r = fmaxf(r, X[i*4+2] + Y[2*4+j]);
      r = fmaxf(r, X[i*4+3] + Y[3*4+j]);
      Z[i*4+j] = r;
    }
  }
}

// chunk matrix: product of 8 per-step sparse trellis matrices (later applied on left)
// M[s'][s] = best path metric from state s to s' over the 8 steps, normalized to max 0
__device__ __forceinline__ void buildM(const float* p, const float* q, float* M) {
  float ppq = p[0] + q[0], pmq = p[0] - q[0];
  M[0]  = -ppq; M[1]  =  ppq; M[2]  = NEGV; M[3]  = NEGV;
  M[4]  = NEGV; M[5]  = NEGV; M[6]  =  pmq; M[7]  = -pmq;
  M[8]  =  ppq; M[9]  = -ppq; M[10] = NEGV; M[11] = NEGV;
  M[12] = NEGV; M[13] = NEGV; M[14] = -pmq; M[15] =  pmq;
#pragma unroll
  for (int k = 1; k < 8; ++k) {
    ppq = p[k] + q[k]; pmq = p[k] - q[k];
#pragma unroll
    for (int j = 0; j < 4; ++j) {
      float r0 = M[0*4+j], r1 = M[1*4+j], r2 = M[2*4+j], r3 = M[3*4+j];
      M[0*4+j] = fmaxf(r0 - ppq, r1 + ppq);
      M[2*4+j] = fmaxf(r0 + ppq, r1 - ppq);
      M[1*4+j] = fmaxf(r2 + pmq, r3 - pmq);
      M[3*4+j] = fmaxf(r2 - pmq, r3 + pmq);
    }
  }
  float mx = max16(M);
#pragma unroll
  for (int e = 0; e < 16; ++e) M[e] -= mx;
}

// One max-log-MAP BCJR pass over the whole row (T=2048), 256 threads x 8 steps.
// Outputs: llr[8] (full LLR at t=8c+k) and p[8] (0.5*(Lc*ys+La)) for extrinsic calc.
template <bool GATHER>
__device__ void bcjr_pass(const float* ys, const float* yp, const float* La,
                          const unsigned short* perm, float* scan,
                          int c, float (&p)[8], float (&llr)[8]) {
  float q[8];
#pragma unroll
  for (int k = 0; k < 8; ++k) {
    int t = c * 8 + k;
    int j = GATHER ? (int)perm[t] : t;
    p[k] = 0.5f * (LCC * ys[j] + La[j]);
    q[k] = (0.5f * LCC) * yp[t];
  }

  float M[16];
  buildM(p, q, M);
#pragma unroll
  for (int e = 0; e < 16; ++e) scan[e*BLK + c] = M[e];
  __syncthreads();

  // forward inclusive scan: P_c = M_c (x) ... (x) M_0
  for (int d = 1; d < BLK; d <<= 1) {
    float P[16];
    bool act = (c >= d);
    if (act) {
#pragma unroll
      for (int e = 0; e < 16; ++e) P[e] = scan[e*BLK + (c - d)];
    }
    __syncthreads();
    if (act) {
      float N[16];
      combine16(M, P, N);           // current after earlier
      float mx = max16(N);
#pragma unroll
      for (int e = 0; e < 16; ++e) { M[e] = N[e] - mx; scan[e*BLK + c] = M[e]; }
    }
    __syncthreads();
  }

  // alpha at chunk start = P_{c-1} (x) alpha0, alpha0 = (0,NEG,NEG,NEG)
  float a[4];
  if (c == 0) { a[0] = 0.f; a[1] = NEGV; a[2] = NEGV; a[3] = NEGV; }
  else {
#pragma unroll
    for (int i = 0; i < 4; ++i) {
      float p0 = scan[(i*4+0)*BLK + (c-1)];
      float p1 = scan[(i*4+1)*BLK + (c-1)];
      float p2 = scan[(i*4+2)*BLK + (c-1)];
      float p3 = scan[(i*4+3)*BLK + (c-1)];
      a[i] = fmaxf(p0, fmaxf(fmaxf(p1, p2), p3) + NEGV);
    }
    float mx = fmaxf(fmaxf(a[0], a[1]), fmaxf(a[2], a[3]));
    a[0] -= mx; a[1] -= mx; a[2] -= mx; a[3] -= mx;
  }
  __syncthreads();

  // rebuild chunk matrices, backward (suffix) scan: Q_c = M_{C-1} (x) ... (x) M_c
  buildM(p, q, M);
#pragma unroll
  for (int e = 0; e < 16; ++e) scan[e*BLK + c] = M[e];
  __syncthreads();
  for (int d = 1; d < BLK; d <<= 1) {
    float P[16];
    bool act = (c + d < BLK);
    if (act) {
#pragma unroll
      for (int e = 0; e < 16; ++e) P[e] = scan[e*BLK + (c + d)];
    }
    __syncthreads();
    if (act) {
      float N[16];
      combine16(P, M, N);           // later applied after earlier
      float mx = max16(N);
#pragma unroll
      for (int e = 0; e < 16; ++e) { M[e] = N[e] - mx; scan[e*BLK + c] = M[e]; }
    }
    __syncthreads();
  }

  // beta at chunk end = Q_{c+1}^T (x) 0  ->  b[s] = max_i Q[i][s]
  float bv[4];
  if (c == BLK - 1) { bv[0] = bv[1] = bv[2] = bv[3] = 0.f; }
  else {
#pragma unroll
    for (int j = 0; j < 4; ++j) {
      float q0 = scan[(0*4+j)*BLK + (c+1)];
      float q1 = scan[(1*4+j)*BLK + (c+1)];
      float q2 = scan[(2*4+j)*BLK + (c+1)];
      float q3 = scan[(3*4+j)*BLK + (c+1)];
      bv[j] = fmaxf(fmaxf(q0, q1), fmaxf(q2, q3));
    }
    float mx = fmaxf(fmaxf(bv[0], bv[1]), fmaxf(bv[2], bv[3]));
    bv[0] -= mx; bv[1] -= mx; bv[2] -= mx; bv[3] -= mx;
  }
  // NOTE: caller must __syncthreads() before reusing `scan`.

  // local beta walk: bet[k] = beta_{8c+k+1}
  float bet[8][4];
  bet[7][0] = bv[0]; bet[7][1] = bv[1]; bet[7][2] = bv[2]; bet[7][3] = bv[3];
#pragma unroll
  for (int k = 7; k >= 1; --k) {
    float ppq = p[k] + q[k], pmq = p[k] - q[k];
    float B0 = bet[k][0], B1 = bet[k][1], B2 = bet[k][2], B3 = bet[k][3];
    bet[k-1][0] = fmaxf(B0 - ppq, B2 + ppq);
    bet[k-1][1] = fmaxf(B2 - ppq, B0 + ppq);
    bet[k-1][2] = fmaxf(B3 - pmq, B1 + pmq);
    bet[k-1][3] = fmaxf(B1 - pmq, B3 + pmq);
  }

  // alpha walk + LLR
#pragma unroll
  for (int k = 0; k < 8; ++k) {
    float ppq = p[k] + q[k], pmq = p[k] - q[k];
    float B0 = bet[k][0], B1 = bet[k][1], B2 = bet[k][2], B3 = bet[k][3];
    float m1 = fmaxf(fmaxf(a[0] + ppq + B2, a[1] + ppq + B0),
                     fmaxf(a[2] + pmq + B1, a[3] + pmq + B3));
    float m0 = fmaxf(fmaxf(a[0] - ppq + B0, a[1] - ppq + B2),
                     fmaxf(a[2] - pmq + B3, a[3] - pmq + B1));
    llr[k] = m1 - m0;
    float a0 = a[0], a1 = a[1], a2 = a[2], a3 = a[3];
    a[0] = fmaxf(a0 - ppq, a1 + ppq);
    a[2] = fmaxf(a0 + ppq, a1 - ppq);
    a[1] = fmaxf(a2 + pmq, a3 - pmq);
    a[3] = fmaxf(a2 - pmq, a3 + pmq);
  }
}

__global__ __launch_bounds__(BLK, 2) void turbo_kernel(
    const int* __restrict__ xg, const float* __restrict__ n1g,
    const float* __restrict__ n2g, const float* __restrict__ n3g,
    const int* __restrict__ pg, float* __restrict__ outg) {
  __shared__ SM sm;
  const int b = blockIdx.x;
  const int c = threadIdx.x;
  const size_t rb = (size_t)b * KLEN;

  // ---- load row inputs (coalesced); bits land in A (as int), noise in y2/y3 ----
  int* Ai = (int*)sm.A;
  for (int i = c; i < KLEN; i += BLK) {
    int xv = xg[rb + i];
    Ai[i] = xv;
    sm.y1[i] = (2.f * xv - 1.f) + n1g[rb + i];
    sm.y2[i] = n2g[rb + i];
    sm.y3[i] = n3g[rb + i];
    sm.Lint[i] = 0.f;
    sm.perm[i] = (unsigned short)pg[i];
  }
  __syncthreads();

  // ---- RSC encode (both parities) via FSM function-composition scan ----
  unsigned int* scanI = (unsigned int*)sm.scan;
  for (int enc = 0; enc < 2; ++enc) {
    unsigned int m = 0x03020100u;   // identity map, byte s = next state
#pragma unroll
    for (int k = 0; k < 8; ++k) {
      int t = c * 8 + k;
      int u = (enc == 0) ? Ai[t] : Ai[sm.perm[t]];
      unsigned int st = u ? 0x03010002u : 0x01030200u;
      unsigned int nm = 0;
#pragma unroll
      for (int s = 0; s < 4; ++s) {
        unsigned int fs = (m >> (8 * s)) & 3u;
        nm |= ((st >> (8 * fs)) & 0xFFu) << (8 * s);
      }
      m = nm;
    }
    scanI[c] = m;
    __syncthreads();
    for (int d = 1; d < BLK; d <<= 1) {
      unsigned int pm = 0;
      bool act = (c >= d);
      if (act) pm = scanI[c - d];
      __syncthreads();
      if (act) {
        unsigned int nm = 0;
#pragma unroll
        for (int s = 0; s < 4; ++s) {
          unsigned int fs = (pm >> (8 * s)) & 3u;
          nm |= ((m >> (8 * fs)) & 0xFFu) << (8 * s);
        }
        m = nm;
        scanI[c] = m;
      }
      __syncthreads();
    }
    int s = 0;
    if (c > 0) s = (int)(scanI[c - 1] & 3u);
    __syncthreads();  // protect scanI before next enc reuses it
    float* ybuf = (enc == 0) ? sm.y2 : sm.y3;
#pragma unroll
    for (int k = 0; k < 8; ++k) {
      int t = c * 8 + k;
      int u = (enc == 0) ? Ai[t] : Ai[sm.perm[t]];
      int s1 = s >> 1, s2 = s & 1;
      int aa = u ^ s1 ^ s2;
      int par = aa ^ s2;
      ybuf[t] = ybuf[t] + (2.f * par - 1.f);  // noise preloaded, add BPSK symbol
      s = (aa << 1) | s1;
    }
    __syncthreads();
  }

  // ---- 6 turbo iterations, 2 BCJR passes each ----
  float p[8], llr[8];
  for (int it = 0; it < 6; ++it) {
    // decoder 1: sys=y1, par=y2, La=L_int
    bcjr_pass<false>(sm.y1, sm.y2, sm.Lint, sm.perm, sm.scan, c, p, llr);
#pragma unroll
    for (int k = 0; k < 8; ++k) sm.A[c * 8 + k] = llr[k] - 2.f * p[k];  // Le1
    __syncthreads();
    // decoder 2: sys=y1 (interleaved), par=y3, La=Le1 (interleaved) — gather via perm
    bcjr_pass<true>(sm.y1, sm.y3, sm.A, sm.perm, sm.scan, c, p, llr);
    __syncthreads();  // all threads done reading `scan`
    if (it < 5) {
#pragma unroll
      for (int k = 0; k < 8; ++k)
        sm.Lint[sm.perm[c * 8 + k]] = llr[k] - 2.f * p[k];  // deinterleaved Le2
      __syncthreads();
    }
  }

  // ---- final: out = deinterleave(L2): stage scatter in LDS, coalesced write ----
  float* stage = sm.scan;
#pragma unroll
  for (int k = 0; k < 8; ++k) stage[sm.perm[c * 8 + k]] = llr[k];
  __syncthreads();
  for (int i = c; i < KLEN; i += BLK) outg[rb + i] = stage[i];
}

extern "C" void kernel_launch(void* const* d_in, const int* in_sizes, int n_in,
                              void* d_out, int out_size, void* d_ws, size_t ws_size,
                              hipStream_t stream) {
  (void)n_in; (void)d_ws; (void)ws_size; (void)out_size;
  const int* x    = (const int*)d_in[0];
  const float* n1 = (const float*)d_in[1];
  const float* n2 = (const float*)d_in[2];
  const float* n3 = (const float*)d_in[3];
  const int* perm = (const int*)d_in[4];
  float* out = (float*)d_out;
  const int K = in_sizes[4];       // 2048
  const int B = in_sizes[0] / K;   // 512
  turbo_kernel<<<B, BLK, 0, stream>>>(x, n1, n2, n3, perm, out);
}

// Round 2
// 190.954 us; speedup vs baseline: 1.1539x; 1.1539x over previous
//
#include <hip/hip_runtime.h>

#define KLEN 2048
#define SCH 16          // trellis steps per thread
#define TPR 128         // threads per row (= KLEN/SCH)
#define NEGV (-1e4f)

struct SM {
  float y1[KLEN];
  float Lint[KLEN];
  float A[KLEN];               // Le1 / bits staging / final-output staging
  unsigned short perm[KLEN];
  float fTot[16];
  float bTot[16];
  unsigned int eTot[2];
};

__device__ __forceinline__ unsigned fsm_compose(unsigned f, unsigned g) {
  // (f after g): nm[s] = f[g[s]], 4 states packed one per byte
  unsigned nm = 0;
#pragma unroll
  for (int s = 0; s < 4; ++s) {
    unsigned gs = (g >> (8 * s)) & 3u;
    nm |= ((f >> (8 * gs)) & 0xFFu) << (8 * s);
  }
  return nm;
}

// Z = X (later) (x) Y (earlier) in max-plus, normalized by Z[0]
__device__ __forceinline__ void comb(const float* X, const float* Y, float* Z) {
#pragma unroll
  for (int i = 0; i < 4; ++i)
#pragma unroll
    for (int j = 0; j < 4; ++j)
      Z[i * 4 + j] = fmaxf(fmaxf(X[i * 4 + 0] + Y[0 * 4 + j], X[i * 4 + 1] + Y[1 * 4 + j]),
                           fmaxf(X[i * 4 + 2] + Y[2 * 4 + j], X[i * 4 + 3] + Y[3 * 4 + j]));
  float z0 = Z[0];
#pragma unroll
  for (int e = 0; e < 16; ++e) Z[e] -= z0;
}

// chunk matrix over SCH steps: M[to][from], normalized to max 0
__device__ __forceinline__ void buildM(const float (&p)[SCH], const float (&q)[SCH], float* M) {
  float ppq = p[0] + q[0], pmq = p[0] - q[0];
  M[0] = -ppq; M[1] =  ppq; M[2] = NEGV; M[3] = NEGV;
  M[4] = NEGV; M[5] = NEGV; M[6] =  pmq; M[7] = -pmq;
  M[8] =  ppq; M[9] = -ppq; M[10] = NEGV; M[11] = NEGV;
  M[12] = NEGV; M[13] = NEGV; M[14] = -pmq; M[15] =  pmq;
#pragma unroll
  for (int k = 1; k < SCH; ++k) {
    ppq = p[k] + q[k]; pmq = p[k] - q[k];
#pragma unroll
    for (int j = 0; j < 4; ++j) {
      float r0 = M[0 * 4 + j], r1 = M[1 * 4 + j], r2 = M[2 * 4 + j], r3 = M[3 * 4 + j];
      M[0 * 4 + j] = fmaxf(r0 - ppq, r1 + ppq);
      M[2 * 4 + j] = fmaxf(r0 + ppq, r1 - ppq);
      M[1 * 4 + j] = fmaxf(r2 + pmq, r3 - pmq);
      M[3 * 4 + j] = fmaxf(r2 - pmq, r3 + pmq);
    }
  }
  float mx = M[0];
#pragma unroll
  for (int e = 1; e < 16; ++e) mx = fmaxf(mx, M[e]);
#pragma unroll
  for (int e = 0; e < 16; ++e) M[e] -= mx;
}

// one max-log-MAP BCJR pass, 128 threads x 16 steps, shuffle scans (2 barriers)
template <int GATHER>
__device__ __forceinline__ void bcjr_pass(
    const float* ys, const float* La, float* dst, int finalLLR,
    const unsigned short* perm, const float (&q)[SCH],
    float (&fTot)[16], float (&bTot)[16],
    int c, int lane, int wr) {
  const int base = c * SCH;
  float p[SCH];
  int pj[SCH];
#pragma unroll
  for (int k = 0; k < SCH; ++k) {
    int t = base + k;
    int j = GATHER ? (int)perm[t] : t;
    if (GATHER) pj[k] = j;
    p[k] = ys[j] + 0.5f * La[j];
  }

  float M[16];
  buildM(p, q, M);

  // fused forward/backward shuffle scans over 64 lanes
  float P[16], Q[16];
#pragma unroll
  for (int e = 0; e < 16; ++e) { P[e] = M[e]; Q[e] = M[e]; }
#pragma unroll
  for (int i = 0; i < 6; ++i) {
    const int d = 1 << i;
    float Tu[16], Td[16];
#pragma unroll
    for (int e = 0; e < 16; ++e) Tu[e] = __shfl_up(P[e], d);
#pragma unroll
    for (int e = 0; e < 16; ++e) Td[e] = __shfl_down(Q[e], d);
    if (lane >= d) {
      float N[16]; comb(P, Tu, N);
#pragma unroll
      for (int e = 0; e < 16; ++e) P[e] = N[e];
    }
    if (lane < 64 - d) {
      float N[16]; comb(Td, Q, N);
#pragma unroll
      for (int e = 0; e < 16; ++e) Q[e] = N[e];
    }
  }

  // cross-wave exchange (single barrier)
  if (wr == 0 && lane == 63) {
#pragma unroll
    for (int e = 0; e < 16; ++e) fTot[e] = P[e];
  }
  if (wr == 1 && lane == 0) {
#pragma unroll
    for (int e = 0; e < 16; ++e) bTot[e] = Q[e];
  }
  __syncthreads();
  if (wr == 1) {
    float T[16], N[16];
#pragma unroll
    for (int e = 0; e < 16; ++e) T[e] = fTot[e];
    comb(P, T, N);
#pragma unroll
    for (int e = 0; e < 16; ++e) P[e] = N[e];
  } else {
    float T[16], N[16];
#pragma unroll
    for (int e = 0; e < 16; ++e) T[e] = bTot[e];
    comb(T, Q, N);
#pragma unroll
    for (int e = 0; e < 16; ++e) Q[e] = N[e];
  }

  // alpha at chunk start = col 0 of inclusive prefix at c-1
  float a[4];
  {
    float t0 = __shfl_up(P[0], 1), t4 = __shfl_up(P[4], 1);
    float t8 = __shfl_up(P[8], 1), t12 = __shfl_up(P[12], 1);
    if (c == 0) { a[0] = 0.f; a[1] = NEGV; a[2] = NEGV; a[3] = NEGV; }
    else {
      if (lane == 0) { a[0] = fTot[0]; a[1] = fTot[4]; a[2] = fTot[8]; a[3] = fTot[12]; }
      else { a[0] = t0; a[1] = t4; a[2] = t8; a[3] = t12; }
      float a0 = a[0]; a[0] = 0.f; a[1] -= a0; a[2] -= a0; a[3] -= a0;
    }
  }

  // beta at chunk end = col-max of inclusive suffix at c+1
  float b[4];
  {
    float bn[16];
#pragma unroll
    for (int e = 0; e < 16; ++e) bn[e] = __shfl_down(Q[e], 1);
    if (c == TPR - 1) { b[0] = b[1] = b[2] = b[3] = 0.f; }
    else {
      if (lane == 63) {
#pragma unroll
        for (int j = 0; j < 4; ++j)
          b[j] = fmaxf(fmaxf(bTot[0 * 4 + j], bTot[1 * 4 + j]),
                       fmaxf(bTot[2 * 4 + j], bTot[3 * 4 + j]));
      } else {
#pragma unroll
        for (int j = 0; j < 4; ++j)
          b[j] = fmaxf(fmaxf(bn[0 * 4 + j], bn[1 * 4 + j]),
                       fmaxf(bn[2 * 4 + j], bn[3 * 4 + j]));
      }
      float b0 = b[0]; b[0] = 0.f; b[1] -= b0; b[2] -= b0; b[3] -= b0;
    }
  }

  // local beta walk: bet[k] = beta_{base+k+1}
  float bet[SCH][4];
  bet[SCH - 1][0] = b[0]; bet[SCH - 1][1] = b[1];
  bet[SCH - 1][2] = b[2]; bet[SCH - 1][3] = b[3];
#pragma unroll
  for (int k = SCH - 1; k >= 1; --k) {
    float ppq = p[k] + q[k], pmq = p[k] - q[k];
    float B0 = bet[k][0], B1 = bet[k][1], B2 = bet[k][2], B3 = bet[k][3];
    bet[k - 1][0] = fmaxf(B0 - ppq, B2 + ppq);
    bet[k - 1][1] = fmaxf(B2 - ppq, B0 + ppq);
    bet[k - 1][2] = fmaxf(B3 - pmq, B1 + pmq);
    bet[k - 1][3] = fmaxf(B1 - pmq, B3 + pmq);
  }

  // alpha walk + LLR + immediate output write
#pragma unroll
  for (int k = 0; k < SCH; ++k) {
    float ppq = p[k] + q[k], pmq = p[k] - q[k];
    float B0 = bet[k][0], B1 = bet[k][1], B2 = bet[k][2], B3 = bet[k][3];
    float m1 = fmaxf(fmaxf(a[0] + ppq + B2, a[1] + ppq + B0),
                     fmaxf(a[2] + pmq + B1, a[3] + pmq + B3));
    float m0 = fmaxf(fmaxf(a[0] - ppq + B0, a[1] - ppq + B2),
                     fmaxf(a[2] - pmq + B3, a[3] - pmq + B1));
    float llr = m1 - m0;
    float val = finalLLR ? llr : (llr - 2.f * p[k]);
    dst[GATHER ? pj[k] : (base + k)] = val;
    float a0 = a[0], a1 = a[1], a2 = a[2], a3 = a[3];
    a[0] = fmaxf(a0 - ppq, a1 + ppq);
    a[2] = fmaxf(a0 + ppq, a1 - ppq);
    a[1] = fmaxf(a2 + pmq, a3 - pmq);
    a[3] = fmaxf(a2 - pmq, a3 + pmq);
  }
}

__global__ __launch_bounds__(TPR, 2) void turbo_kernel(
    const int* __restrict__ xg, const float* __restrict__ n1g,
    const float* __restrict__ n2g, const float* __restrict__ n3g,
    const int* __restrict__ pg, float* __restrict__ outg) {
  __shared__ SM sm;
  const int tid = threadIdx.x;
  const int c = tid, lane = tid & 63, wr = tid >> 6;
  const size_t rb = (size_t)blockIdx.x * KLEN;

  // ---- load: perm, bits->A(int), y1, Lint=0; parity noise -> registers ----
  int* Ai = (int*)sm.A;
  for (int i = tid; i < KLEN; i += TPR) {
    sm.perm[i] = (unsigned short)pg[i];
    int xv = xg[rb + i];
    Ai[i] = xv;
    sm.y1[i] = (2.f * xv - 1.f) + n1g[rb + i];
    sm.Lint[i] = 0.f;
  }
  float q2[SCH], q3[SCH];
  {
    size_t g0 = rb + (size_t)c * SCH;
#pragma unroll
    for (int k = 0; k < SCH; ++k) { q2[k] = n2g[g0 + k]; q3[k] = n3g[g0 + k]; }
  }
  __syncthreads();

  // ---- RSC encode (both parities together) via FSM shuffle scan ----
  unsigned ub1 = 0, ub2 = 0;
#pragma unroll
  for (int k = 0; k < SCH; ++k) {
    int t = c * SCH + k;
    ub1 |= (unsigned)(Ai[t] & 1) << k;
    ub2 |= (unsigned)(Ai[sm.perm[t]] & 1) << k;
  }
  unsigned m1 = 0x03020100u, m2 = 0x03020100u;
#pragma unroll
  for (int k = 0; k < SCH; ++k) {
    unsigned st1 = ((ub1 >> k) & 1) ? 0x03010002u : 0x01030200u;
    unsigned st2 = ((ub2 >> k) & 1) ? 0x03010002u : 0x01030200u;
    m1 = fsm_compose(st1, m1);
    m2 = fsm_compose(st2, m2);
  }
#pragma unroll
  for (int i = 0; i < 6; ++i) {
    const int d = 1 << i;
    unsigned t1 = __shfl_up(m1, d), t2 = __shfl_up(m2, d);
    if (lane >= d) { m1 = fsm_compose(m1, t1); m2 = fsm_compose(m2, t2); }
  }
  if (wr == 0 && lane == 63) { sm.eTot[0] = m1; sm.eTot[1] = m2; }
  __syncthreads();
  {
    unsigned w1 = sm.eTot[0], w2 = sm.eTot[1];
    unsigned f1 = wr ? fsm_compose(m1, w1) : m1;
    unsigned f2 = wr ? fsm_compose(m2, w2) : m2;
    unsigned pf1 = __shfl_up(f1, 1), pf2 = __shfl_up(f2, 1);
    int s1 = (c == 0) ? 0 : (lane == 0 ? (int)(w1 & 3u) : (int)(pf1 & 3u));
    int s2 = (c == 0) ? 0 : (lane == 0 ? (int)(w2 & 3u) : (int)(pf2 & 3u));
#pragma unroll
    for (int k = 0; k < SCH; ++k) {
      { int u = (ub1 >> k) & 1, a = u ^ (s1 >> 1) ^ (s1 & 1), par = a ^ (s1 & 1);
        q2[k] += 2.f * par - 1.f; s1 = (a << 1) | (s1 >> 1); }
      { int u = (ub2 >> k) & 1, a = u ^ (s2 >> 1) ^ (s2 & 1), par = a ^ (s2 & 1);
        q3[k] += 2.f * par - 1.f; s2 = (a << 1) | (s2 >> 1); }
    }
  }
  __syncthreads();  // bits in A consumed; A becomes Le1 buffer

  // ---- 6 turbo iterations ----
#pragma unroll 1
  for (int it = 0; it < 6; ++it) {
    bcjr_pass<0>(sm.y1, sm.Lint, sm.A, 0, sm.perm, q2, sm.fTot, sm.bTot, c, lane, wr);
    __syncthreads();
    const int fin = (it == 5);
    bcjr_pass<1>(sm.y1, sm.A, fin ? sm.A : sm.Lint, fin, sm.perm, q3,
                 sm.fTot, sm.bTot, c, lane, wr);
    __syncthreads();
  }

  // ---- final: A holds deinterleaved L2; coalesced store ----
  for (int i = tid; i < KLEN; i += TPR) outg[rb + i] = sm.A[i];
}

extern "C" void kernel_launch(void* const* d_in, const int* in_sizes, int n_in,
                              void* d_out, int out_size, void* d_ws, size_t ws_size,
                              hipStream_t stream) {
  (void)n_in; (void)d_ws; (void)ws_size; (void)out_size;
  const int* x    = (const int*)d_in[0];
  const float* n1 = (const float*)d_in[1];
  const float* n2 = (const float*)d_in[2];
  const float* n3 = (const float*)d_in[3];
  const int* perm = (const int*)d_in[4];
  float* out = (float*)d_out;
  const int K = in_sizes[4];       // 2048
  const int B = in_sizes[0] / K;   // 512 rows, one per block
  turbo_kernel<<<B, TPR, 0, stream>>>(x, n1, n2, n3, perm, out);
}